// Round 1
// 312.656 us; speedup vs baseline: 1.1150x; 1.1150x over previous
//
#include <hip/hip_runtime.h>
#include <math.h>

#pragma clang fp contract(off)

#define HW      (2048*2048)
#define NI      4096        // instances per image
#define MAXPIX  1024        // pixels per instance (equal partition)
#define NF      200
#define FEAT    209
#define NE      (NI*2)
#define XSIZE   ((2*NI)*FEAT)
#define EIOFF   XSIZE
#define EAOFF   (EIOFF + 2*NE)

#define S       4096        // pixels per chunk (one sort block)
#define CHK     (HW/S)      // 1024 chunks per image
#define TOTCHK  (2*CHK)     // 2048
#define NBPI    256         // buckets per image (16 labels each)
#define LPB     16
#define NBG     (2*NBPI)    // 512 global buckets
#define REC     (2*HW)
#define CBLK    (TOTCHK/4)  // count blocks (4 chunks each) = 512
#define BTOT    (LPB*MAXPIX) // 16384 records per bucket (equal partition => static)

template<int NB>
__device__ __forceinline__ unsigned long long match_bits(int v) {
    unsigned long long m = ~0ull;
    #pragma unroll
    for (int bit = 0; bit < NB; ++bit) {
        unsigned long long bb = __ballot((v >> bit) & 1);
        m &= ((v >> bit) & 1) ? bb : ~bb;
    }
    return m;
}

// ---- pass 1: per-chunk bucket counts + per-block per-label fz partials ---
__global__ void __launch_bounds__(256) count_zf_kernel(const int* __restrict__ mask1,
        const int* __restrict__ mask2, const float* __restrict__ flow1,
        const float* __restrict__ flow2, unsigned* __restrict__ cntA,
        float* __restrict__ zfpart) {
    __shared__ unsigned cnt[4][NBPI];    // 4 KB
    __shared__ float zfp[NI];            // 16 KB
    int w = threadIdx.x >> 6, lane = threadIdx.x & 63;
    for (int j = threadIdx.x; j < 4*NBPI; j += 256) ((unsigned*)cnt)[j] = 0u;
    for (int j = threadIdx.x; j < NI; j += 256) zfp[j] = 0.f;
    __syncthreads();
    int c = blockIdx.x * 4 + w;                 // per-wave chunk; all 4 same image
    int img = c / CHK;
    const int4*   mask  = (const int4*)(img ? mask2 : mask1);
    const float4* flowz = (const float4*)((img ? flow2 : flow1) + 2L*HW);
    long base4 = (long)(c - img*CHK) * (S/4);
    for (int t = 0; t < S/4; t += 64) {
        int4   l4 = mask[base4 + t + lane];
        float4 fz = flowz[base4 + t + lane];
        atomicAdd(&cnt[w][(l4.x-1) >> 4], 1u);
        atomicAdd(&cnt[w][(l4.y-1) >> 4], 1u);
        atomicAdd(&cnt[w][(l4.z-1) >> 4], 1u);
        atomicAdd(&cnt[w][(l4.w-1) >> 4], 1u);
        atomicAdd(&zfp[l4.x-1], fz.x);
        atomicAdd(&zfp[l4.y-1], fz.y);
        atomicAdd(&zfp[l4.z-1], fz.z);
        atomicAdd(&zfp[l4.w-1], fz.w);
    }
    __syncthreads();
    unsigned* dst = cntA + (long)c * NBPI;
    for (int j = lane; j < NBPI; j += 64) dst[j] = cnt[w][j];
    float* zdst = zfpart + (long)blockIdx.x * NI;
    for (int j = threadIdx.x; j < NI; j += 256) zdst[j] = zfp[j];
}

// ---- pass 2: per-bucket chunk scan (shfl, 2 barriers) + fused zf means ---
__global__ void __launch_bounds__(256) scan1_zf_kernel(unsigned* __restrict__ cntA,
        const float* __restrict__ zfpart, float* __restrict__ zfm) {
    __shared__ int wsum[4];
    __shared__ float zsh[4][LPB];
    int gb = blockIdx.x;
    int img = gb >> 8, lb = gb & (NBPI - 1);
    int t = threadIdx.x, lane = t & 63, w = t >> 6;
    const int PER = CHK / 256;   // 4 chunks per thread
    unsigned e[PER]; int s = 0;
    long base = ((long)img * CHK + (long)t * PER) * NBPI + lb;
    #pragma unroll
    for (int i = 0; i < PER; ++i) { e[i] = cntA[base + (long)i * NBPI]; s += (int)e[i]; }
    int incl = s;
    #pragma unroll
    for (int off = 1; off < 64; off <<= 1) {
        int o = __shfl_up(incl, off);
        if (lane >= off) incl += o;
    }
    if (lane == 63) wsum[w] = incl;
    __syncthreads();
    int add = 0;
    for (int q = 0; q < w; ++q) add += wsum[q];
    unsigned pre = (unsigned)(incl + add - s);
    #pragma unroll
    for (int i = 0; i < PER; ++i) { unsigned cv = e[i]; cntA[base + (long)i * NBPI] = pre; pre += cv; }
    // fused zf reduction: this block's 16 labels, 256 partials, float4-coalesced
    {
        int li0 = gb * LPB;                       // global label base (0..8191)
        int zimg = li0 >> 12, l0 = li0 & (NI-1);
        const float4* zp = (const float4*)(zfpart + (long)zimg*(CBLK/2)*NI + (long)t*NI + l0);
        float4 a0 = zp[0], a1 = zp[1], a2 = zp[2], a3 = zp[3];   // 64B/thread, full line
        #pragma unroll
        for (int off = 1; off < 64; off <<= 1) {
            a0.x += __shfl_xor(a0.x, off); a0.y += __shfl_xor(a0.y, off);
            a0.z += __shfl_xor(a0.z, off); a0.w += __shfl_xor(a0.w, off);
            a1.x += __shfl_xor(a1.x, off); a1.y += __shfl_xor(a1.y, off);
            a1.z += __shfl_xor(a1.z, off); a1.w += __shfl_xor(a1.w, off);
            a2.x += __shfl_xor(a2.x, off); a2.y += __shfl_xor(a2.y, off);
            a2.z += __shfl_xor(a2.z, off); a2.w += __shfl_xor(a2.w, off);
            a3.x += __shfl_xor(a3.x, off); a3.y += __shfl_xor(a3.y, off);
            a3.z += __shfl_xor(a3.z, off); a3.w += __shfl_xor(a3.w, off);
        }
        if (lane == 0) {
            zsh[w][0]=a0.x; zsh[w][1]=a0.y; zsh[w][2]=a0.z; zsh[w][3]=a0.w;
            zsh[w][4]=a1.x; zsh[w][5]=a1.y; zsh[w][6]=a1.z; zsh[w][7]=a1.w;
            zsh[w][8]=a2.x; zsh[w][9]=a2.y; zsh[w][10]=a2.z; zsh[w][11]=a2.w;
            zsh[w][12]=a3.x; zsh[w][13]=a3.y; zsh[w][14]=a3.z; zsh[w][15]=a3.w;
        }
        __syncthreads();
        if (t < LPB) {
            float sum = zsh[0][t] + zsh[1][t] + zsh[2][t] + zsh[3][t];
            zfm[gb*LPB + t] = sum * (1.0f/(float)MAXPIX);   // exact /1024
        }
    }
}

// ---- pass 3: LDS-staged stable bucket sort (prefetch + shfl scan, 4 barriers)
__global__ void __launch_bounds__(512) sort_kernel(
        const float* __restrict__ img1, const float* __restrict__ img2,
        const float* __restrict__ flow1, const float* __restrict__ flow2,
        const int* __restrict__ mask1, const int* __restrict__ mask2,
        const unsigned* __restrict__ cntA,
        float* __restrict__ riv, unsigned char* __restrict__ rmeta) {
    __shared__ float ivs[S];                     // 16 KB
    __shared__ unsigned short smeta[S];          // 8 KB  (bkt<<8 | bin<<4 | ll)
    __shared__ unsigned short cw[8][NBPI];       // 4 KB  (counts -> cursors)
    __shared__ int gofs[NBPI];                   // 1 KB
    __shared__ int wsum[4];
    int t = threadIdx.x, w = t >> 6, lane = t & 63;
    int c = blockIdx.x;
    int img = c / CHK;
    const int*   mask  = img ? mask2  : mask1;
    const float* image = img ? img2   : img1;
    const float* flow  = img ? flow2  : flow1;
    long base = (long)(c - img*CHK) * S;
    for (int j = t; j < 8*NBPI; j += 512) ((unsigned short*)cw)[j] = 0;
    __syncthreads();
    // phase 1: prefetch everything + ballots; pack l|bin|cb|ct into one reg
    long qbase = base + (long)w * (S/8);
    int   pk[8];
    float piv[8];
    unsigned long long ltmask = (1ull << lane) - 1ull;
    #pragma unroll
    for (int it = 0; it < 8; ++it) {
        long p = qbase + it*64 + lane;
        int l = mask[p] - 1;
        piv[it] = image[p];
        float fx = flow[p], fy = flow[HW + p];
        int cx = fx < 0.f ? 0 : (fx == 0.f ? 1 : 2);
        int cy = fy < 0.f ? 0 : (fy == 0.f ? 1 : 2);
        int bkt = l >> 4;
        unsigned long long m = match_bits<8>(bkt);
        int cb = __popcll(m & ltmask);
        int ct = __popcll(m);
        pk[it] = l | ((cx*3 + cy) << 12) | (cb << 16) | (ct << 22);
        if (cb == 0) cw[w][bkt] += (unsigned short)ct;   // leaders: distinct addrs
    }
    __syncthreads();
    // block scan over 256 buckets via wave shfl (threads 0..255)
    int tot = 0, incl = 0;
    if (t < NBPI) {
        #pragma unroll
        for (int q = 0; q < 8; ++q) tot += cw[q][t];
        incl = tot;
        #pragma unroll
        for (int off = 1; off < 64; off <<= 1) {
            int o = __shfl_up(incl, off);
            if (lane >= off) incl += o;
        }
        if (lane == 63) wsum[w] = incl;
    }
    __syncthreads();
    if (t < NBPI) {
        int add = 0;
        for (int q = 0; q < w; ++q) add += wsum[q];
        int excl = incl + add - tot;                 // chunk-local bucket offset
        int run = excl;
        #pragma unroll
        for (int q = 0; q < 8; ++q) {
            int cq = cw[q][t];
            cw[q][t] = (unsigned short)run;
            run += cq;
        }
        // static bucketBase: gb*BTOT (equal partition)
        gofs[t] = (img*NBPI + t) * BTOT + (int)cntA[(long)c * NBPI + t] - excl;
    }
    __syncthreads();
    // phase 2: place records (no loads, no ballots — all cached in pk/piv)
    #pragma unroll
    for (int it = 0; it < 8; ++it) {
        int pkv = pk[it];
        int l = pkv & 4095, bin = (pkv >> 12) & 15;
        int cb = (pkv >> 16) & 63, ct = (pkv >> 22) & 127;
        int bkt = l >> 4;
        int r0 = (int)cw[w][bkt];
        int dst = r0 + cb;
        if (cb == ct - 1) cw[w][bkt] = (unsigned short)(r0 + ct);
        ivs[dst] = piv[it];
        smeta[dst] = (unsigned short)((bkt << 8) | (bin << 4) | (l & 15));
    }
    __syncthreads();
    // phase 3: linear flush — consecutive j => contiguous global runs
    for (int j = t; j < S; j += 512) {
        int ms = (int)smeta[j];
        int b = ms >> 8;
        int g = gofs[b] + j;
        riv[g]   = ivs[j];
        rmeta[g] = (unsigned char)(ms & 0xFF);
    }
}

// ---- pass 4: fused rank + features; static totals, in-LDS interp table ----
__global__ void __launch_bounds__(512) stageB_kernel(
        const float* __restrict__ riv, const unsigned char* __restrict__ rmeta,
        float* __restrict__ out) {
    __shared__ float acc[LPB * NF];          // 12.8 KB
    __shared__ float s_tw[MAXPIX];
    __shared__ int   s_tk[MAXPIX];
    __shared__ int   hist[LPB * 9];
    __shared__ unsigned qc[8][LPB];
    __shared__ int   cur[8][LPB];
    int t = threadIdx.x, w = t >> 6, lane = t & 63;
    int gb = blockIdx.x;
    for (int j = t; j < LPB*NF; j += 512) acc[j] = 0.f;
    for (int j = t; j < MAXPIX; j += 512) s_tk[j] = -1;
    for (int j = t; j < LPB*9; j += 512) hist[j] = 0;
    for (int j = t; j < 8*LPB; j += 512) ((unsigned*)qc)[j] = 0u;
    __syncthreads();
    if (t < NF) {                            // static table (cnt == MAXPIX)
        const float Lf = (float)MAXPIX;
        float p = ((float)t + 0.5f) * (Lf / (float)NF) - 0.5f;
        p = fminf(fmaxf(p, 0.0f), Lf - 1.0f);
        int i0 = (int)floorf(p);
        int i1 = min(i0 + 1, MAXPIX - 1);
        float wg = p - (float)i0;
        s_tk[i0] = t; s_tw[i0] = 1.0f - wg;  // spacing 5.12 => no collision
        s_tk[i1] = t; s_tw[i1] = wg;
    }
    long base = (long)gb * BTOT;
    const int qsz = BTOT / 8;                // 2048 (exact => no bounds checks)
    int qbeg = w * qsz;
    const int nit = qsz / 64;                // 32
    // phase 1: per-segment per-label counts (LDS atomics — order-free)
    for (int it = 0; it < nit; ++it) {
        int i = qbeg + it*64 + lane;
        atomicAdd(&qc[w][rmeta[base + i] & 15], 1u);
    }
    __syncthreads();
    if (t < LPB) {
        int s = 0;
        #pragma unroll
        for (int q = 0; q < 8; ++q) { cur[q][t] = s; s += (int)qc[q][t]; }
    }
    __syncthreads();
    // phase 2: stable rank + reduce (all lanes valid)
    for (int it = 0; it < nit; ++it) {
        int i = qbeg + it*64 + lane;
        int meta = (int)rmeta[base + i];
        float iv = riv[base + i];
        int ll = meta & 15, bin = meta >> 4;
        unsigned long long m = match_bits<4>(ll);
        int cb = __popcll(m & ((1ull << lane) - 1ull));
        int ct = __popcll(m);
        int r0 = cur[w][ll];
        int rank = r0 + cb;
        if (cb == ct - 1) cur[w][ll] = r0 + ct;
        atomicAdd(&hist[ll*9 + bin], 1);
        int k = s_tk[rank];
        if (k >= 0) atomicAdd(&acc[ll*NF + k], iv * s_tw[rank]);  // commutative-exact pair
    }
    __syncthreads();
    if (t < FEAT) {
        for (int r = 0; r < LPB; ++r) {
            long gl = (long)gb * LPB + r;
            out[gl * FEAT + t] = (t < NF) ? acc[r*NF + t] : (float)hist[r*9 + (t - NF)];
        }
    }
}

// ---- edges: top-2 nearest centers (bbox2 x/y LDS-staged) ------------------
__device__ __forceinline__ bool better(float d, int j, float d2, int j2) {
    return d < d2 || (d == d2 && j < j2);
}

__global__ void __launch_bounds__(256) edge_kernel(const float* __restrict__ bbox1,
                                                   const float* __restrict__ bbox2,
                                                   const float* __restrict__ zfm,
                                                   float* __restrict__ out) {
    __shared__ float sbx[NI], sby[NI];       // 32 KB
    int wave = threadIdx.x >> 6, lane = threadIdx.x & 63;
    for (int r = threadIdx.x; r < NI; r += 256) {
        float4 b = ((const float4*)bbox2)[r];
        sbx[r] = b.x; sby[r] = b.y;
    }
    __syncthreads();
    int i = blockIdx.x * 4 + wave;
    float c1x = bbox1[i*4 + 0], c1y = bbox1[i*4 + 1];
    float d0 = INFINITY; int j0 = 0x7fffffff;
    float d1 = INFINITY; int j1 = 0x7fffffff;
    for (int t = 0; t < NI; t += 64) {
        int j = t + lane;
        float dx = c1x - sbx[j];
        float dy = c1y - sby[j];
        float dsq = dx*dx + dy*dy;                 // no fma (contract off)
        float d = (float)sqrt((double)dsq);        // correctly-rounded f32 sqrt
        if (better(d, j, d0, j0)) { d1 = d0; j1 = j0; d0 = d; j0 = j; }
        else if (better(d, j, d1, j1)) { d1 = d; j1 = j; }
    }
    for (int off = 32; off; off >>= 1) {
        float od0 = __shfl_down(d0, off); int oj0 = __shfl_down(j0, off);
        float od1 = __shfl_down(d1, off); int oj1 = __shfl_down(j1, off);
        if (better(od0, oj0, d0, j0)) {
            if (better(d0, j0, od1, oj1)) { d1 = d0; j1 = j0; }
            else                          { d1 = od1; j1 = oj1; }
            d0 = od0; j0 = oj0;
        } else if (better(od0, oj0, d1, j1)) { d1 = od0; j1 = oj0; }
    }
    if (lane == 0) {
        float z1 = zfm[i];
        int js[2] = { j0, j1 };
        for (int t = 0; t < 2; ++t) {
            int e = i*2 + t, j = js[t];
            out[EIOFF + e]      = (float)i;
            out[EIOFF + NE + e] = (float)(j + NI);
            float* ea = out + EAOFF + (long)e * 6;
            ea[0] = z1;
            ea[1] = zfm[NI + j];
            ea[2] = c1x - bbox2[j*4 + 0];
            ea[3] = c1y - bbox2[j*4 + 1];
            ea[4] = bbox1[i*4 + 2] / bbox2[j*4 + 2];
            ea[5] = bbox1[i*4 + 3] / bbox2[j*4 + 3];
        }
    }
}

extern "C" void kernel_launch(void* const* d_in, const int* in_sizes, int n_in,
                              void* d_out, int out_size, void* d_ws, size_t ws_size,
                              hipStream_t stream) {
    const float* img1  = (const float*)d_in[0];
    const float* img2  = (const float*)d_in[1];
    const float* flow1 = (const float*)d_in[2];
    const float* flow2 = (const float*)d_in[3];
    const float* bbox1 = (const float*)d_in[4];
    const float* bbox2 = (const float*)d_in[5];
    const int*   mask1 = (const int*)d_in[6];
    const int*   mask2 = (const int*)d_in[7];
    float* out = (float*)d_out;

    char* ws = (char*)d_ws;
    size_t off = 0;
    unsigned* cntA   = (unsigned*)(ws + off); off += (size_t)TOTCHK * NBPI * 4;  // 2 MB
    float*    riv    = (float*)(ws + off);    off += (size_t)REC * 4;            // 33.5 MB
    float*    zfpart = (float*)(ws + off);    off += (size_t)CBLK * NI * 4;      // 8.4 MB
    float*    zfm    = (float*)(ws + off);    off += 2 * NI * 4;
    unsigned char* rmeta = (unsigned char*)(ws + off); off += (size_t)REC;       // 8.4 MB

    hipLaunchKernelGGL(count_zf_kernel, dim3(CBLK), dim3(256), 0, stream,
                       mask1, mask2, flow1, flow2, cntA, zfpart);
    hipLaunchKernelGGL(scan1_zf_kernel, dim3(NBG), dim3(256), 0, stream,
                       cntA, zfpart, zfm);
    hipLaunchKernelGGL(sort_kernel, dim3(TOTCHK), dim3(512), 0, stream,
                       img1, img2, flow1, flow2, mask1, mask2, cntA, riv, rmeta);
    hipLaunchKernelGGL(stageB_kernel, dim3(NBG), dim3(512), 0, stream,
                       riv, rmeta, out);
    hipLaunchKernelGGL(edge_kernel, dim3(NI/4), dim3(256), 0, stream,
                       bbox1, bbox2, zfm, out);
}

// Round 2
// 311.308 us; speedup vs baseline: 1.1198x; 1.0043x over previous
//
#include <hip/hip_runtime.h>
#include <math.h>

#pragma clang fp contract(off)

#define HW      (2048*2048)
#define NI      4096        // instances per image
#define MAXPIX  1024        // pixels per instance (equal partition)
#define NF      200
#define FEAT    209
#define NE      (NI*2)
#define XSIZE   ((2*NI)*FEAT)
#define EIOFF   XSIZE
#define EAOFF   (EIOFF + 2*NE)

#define S       8192        // pixels per chunk (one sort block)
#define CHK     (HW/S)      // 512 chunks per image
#define TOTCHK  (2*CHK)     // 1024
#define NBPI    256         // buckets per image (16 labels each)
#define LPB     16
#define NBG     (2*NBPI)    // 512 global buckets
#define REC     (2*HW)
#define CBLK    (TOTCHK/4)  // count blocks (4 chunks each) = 256
#define BTOT    (LPB*MAXPIX) // 16384 records per bucket (equal partition => static)

template<int NB>
__device__ __forceinline__ unsigned long long match_bits(int v) {
    unsigned long long m = ~0ull;
    #pragma unroll
    for (int bit = 0; bit < NB; ++bit) {
        unsigned long long bb = __ballot((v >> bit) & 1);
        m &= ((v >> bit) & 1) ? bb : ~bb;
    }
    return m;
}

// ---- pass 1: per-chunk bucket counts + per-block per-label fz partials ---
__global__ void __launch_bounds__(256) count_zf_kernel(const int* __restrict__ mask1,
        const int* __restrict__ mask2, const float* __restrict__ flow1,
        const float* __restrict__ flow2, unsigned* __restrict__ cntA,
        float* __restrict__ zfpart) {
    __shared__ unsigned cnt[4][NBPI];    // 4 KB
    __shared__ float zfp[NI];            // 16 KB
    int w = threadIdx.x >> 6, lane = threadIdx.x & 63;
    for (int j = threadIdx.x; j < 4*NBPI; j += 256) ((unsigned*)cnt)[j] = 0u;
    for (int j = threadIdx.x; j < NI; j += 256) zfp[j] = 0.f;
    __syncthreads();
    int c = blockIdx.x * 4 + w;                 // per-wave chunk of S px
    int img = c / CHK;
    const int4*   mask  = (const int4*)(img ? mask2 : mask1);
    const float4* flowz = (const float4*)((img ? flow2 : flow1) + 2L*HW);
    long base4 = (long)(c - img*CHK) * (S/4);
    for (int t = 0; t < S/4; t += 64) {
        int4   l4 = mask[base4 + t + lane];
        float4 fz = flowz[base4 + t + lane];
        atomicAdd(&cnt[w][(l4.x-1) >> 4], 1u);
        atomicAdd(&cnt[w][(l4.y-1) >> 4], 1u);
        atomicAdd(&cnt[w][(l4.z-1) >> 4], 1u);
        atomicAdd(&cnt[w][(l4.w-1) >> 4], 1u);
        atomicAdd(&zfp[l4.x-1], fz.x);
        atomicAdd(&zfp[l4.y-1], fz.y);
        atomicAdd(&zfp[l4.z-1], fz.z);
        atomicAdd(&zfp[l4.w-1], fz.w);
    }
    __syncthreads();
    unsigned* dst = cntA + (long)c * NBPI;
    for (int j = lane; j < NBPI; j += 64) dst[j] = cnt[w][j];
    float* zdst = zfpart + (long)blockIdx.x * NI;
    for (int j = threadIdx.x; j < NI; j += 256) zdst[j] = zfp[j];
}

// ---- pass 2: per-bucket chunk scan (shfl) + fused zf means ---------------
__global__ void __launch_bounds__(256) scan1_zf_kernel(unsigned* __restrict__ cntA,
        const float* __restrict__ zfpart, float* __restrict__ zfm) {
    __shared__ int wsum[4];
    __shared__ float zpar[16][LPB];
    int gb = blockIdx.x;
    int img = gb >> 8, lb = gb & (NBPI - 1);
    int t = threadIdx.x, lane = t & 63, w = t >> 6;
    const int PER = CHK / 256;   // 2 chunks per thread
    unsigned e[PER]; int s = 0;
    long base = ((long)img * CHK + (long)t * PER) * NBPI + lb;
    #pragma unroll
    for (int i = 0; i < PER; ++i) { e[i] = cntA[base + (long)i * NBPI]; s += (int)e[i]; }
    int incl = s;
    #pragma unroll
    for (int off = 1; off < 64; off <<= 1) {
        int o = __shfl_up(incl, off);
        if (lane >= off) incl += o;
    }
    if (lane == 63) wsum[w] = incl;
    __syncthreads();
    int add = 0;
    for (int q = 0; q < w; ++q) add += wsum[q];
    unsigned pre = (unsigned)(incl + add - s);
    #pragma unroll
    for (int i = 0; i < PER; ++i) { unsigned cv = e[i]; cntA[base + (long)i * NBPI] = pre; pre += cv; }
    // fused zf reduction: this bucket's 16 labels over 128 partial rows
    {
        int li0 = gb * LPB;
        int zimg = li0 >> 12, l0 = li0 & (NI-1);
        int lab = t & 15, rg = t >> 4;           // 16 row-groups x 16 labels
        const float* zp = zfpart + (long)(zimg*(CBLK/2) + rg*8)*NI + l0 + lab;
        float s8 = 0.f;
        #pragma unroll
        for (int k = 0; k < 8; ++k) s8 += zp[(long)k*NI];
        zpar[rg][lab] = s8;
    }
    __syncthreads();
    if (t < LPB) {
        float sum = 0.f;
        #pragma unroll
        for (int g = 0; g < 16; ++g) sum += zpar[g][t];
        zfm[gb*LPB + t] = sum * (1.0f/(float)MAXPIX);   // exact /1024
    }
}

// ---- pass 3: LDS-staged stable bucket sort (S=8192, 3 blocks/CU) ---------
__global__ void __launch_bounds__(512) sort_kernel(
        const float* __restrict__ img1, const float* __restrict__ img2,
        const float* __restrict__ flow1, const float* __restrict__ flow2,
        const int* __restrict__ mask1, const int* __restrict__ mask2,
        const unsigned* __restrict__ cntA,
        float* __restrict__ riv, unsigned char* __restrict__ rmeta) {
    __shared__ float ivs[S];                     // 32 KB
    __shared__ unsigned short smeta[S];          // 16 KB  (bkt<<8 | bin<<4 | ll)
    __shared__ unsigned short cw[8][NBPI];       // 4 KB  (counts -> cursors)
    __shared__ int gofs[NBPI];                   // 1 KB   => 54272 B = 106x512
    int* wsum = (int*)smeta;                     // alias: smeta dead until phase 2
    int t = threadIdx.x, w = t >> 6, lane = t & 63;
    int c = blockIdx.x;
    int img = c / CHK;
    const int*   mask  = img ? mask2  : mask1;
    const float* image = img ? img2   : img1;
    const float* flow  = img ? flow2  : flow1;
    long base = (long)(c - img*CHK) * S;
    for (int j = t; j < 8*NBPI; j += 512) ((unsigned short*)cw)[j] = 0;
    __syncthreads();
    // phase 1: prefetch everything + ballots; pack l|bin|cb|ct into one reg
    long qbase = base + (long)w * (S/8);
    int   pk[16];
    float piv[16];
    unsigned long long ltmask = (1ull << lane) - 1ull;
    #pragma unroll
    for (int it = 0; it < 16; ++it) {
        long p = qbase + it*64 + lane;
        int l = mask[p] - 1;
        piv[it] = image[p];
        float fx = flow[p], fy = flow[HW + p];
        int cx = fx < 0.f ? 0 : (fx == 0.f ? 1 : 2);
        int cy = fy < 0.f ? 0 : (fy == 0.f ? 1 : 2);
        int bkt = l >> 4;
        unsigned long long m = match_bits<8>(bkt);
        int cb = __popcll(m & ltmask);
        int ct = __popcll(m);
        pk[it] = l | ((cx*3 + cy) << 12) | (cb << 16) | (ct << 22);
        if (cb == 0) cw[w][bkt] += (unsigned short)ct;   // leaders: distinct addrs
    }
    __syncthreads();
    // block scan over 256 buckets via wave shfl (threads 0..255 = 4 waves)
    int tot = 0, incl = 0;
    if (t < NBPI) {
        #pragma unroll
        for (int q = 0; q < 8; ++q) tot += cw[q][t];
        incl = tot;
        #pragma unroll
        for (int off = 1; off < 64; off <<= 1) {
            int o = __shfl_up(incl, off);
            if (lane >= off) incl += o;
        }
        if (lane == 63) wsum[w] = incl;
    }
    __syncthreads();
    if (t < NBPI) {
        int add = 0;
        for (int q = 0; q < w; ++q) add += wsum[q];
        int excl = incl + add - tot;                 // chunk-local bucket offset
        int run = excl;
        #pragma unroll
        for (int q = 0; q < 8; ++q) {
            int cq = cw[q][t];
            cw[q][t] = (unsigned short)run;
            run += cq;
        }
        // static bucketBase: gb*BTOT (equal partition)
        gofs[t] = (img*NBPI + t) * BTOT + (int)cntA[(long)c * NBPI + t] - excl;
    }
    __syncthreads();
    // phase 2: place records (no loads, no ballots — all cached in pk/piv)
    #pragma unroll
    for (int it = 0; it < 16; ++it) {
        int pkv = pk[it];
        int l = pkv & 4095, bin = (pkv >> 12) & 15;
        int cb = (pkv >> 16) & 63, ct = (pkv >> 22) & 127;
        int bkt = l >> 4;
        int r0 = (int)cw[w][bkt];
        int dst = r0 + cb;
        if (cb == ct - 1) cw[w][bkt] = (unsigned short)(r0 + ct);
        ivs[dst] = piv[it];
        smeta[dst] = (unsigned short)((bkt << 8) | (bin << 4) | (l & 15));
    }
    __syncthreads();
    // phase 3: linear flush — consecutive j => contiguous global runs (32 recs)
    for (int j = t; j < S; j += 512) {
        int ms = (int)smeta[j];
        int b = ms >> 8;
        int g = gofs[b] + j;
        riv[g]   = ivs[j];
        rmeta[g] = (unsigned char)(ms & 0xFF);
    }
}

// ---- pass 4: fused rank + features; meta cached in regs, leader counting --
__global__ void __launch_bounds__(512) stageB_kernel(
        const float* __restrict__ riv, const unsigned char* __restrict__ rmeta,
        float* __restrict__ out) {
    __shared__ float acc[LPB * NF];          // 12.8 KB
    __shared__ float s_tw[MAXPIX];
    __shared__ int   s_tk[MAXPIX];
    __shared__ int   h8[8][LPB * 9];         // per-wave hist (leader writes)
    __shared__ int   qc[8][LPB];
    __shared__ int   cur[8][LPB];
    int t = threadIdx.x, w = t >> 6, lane = t & 63;
    int gb = blockIdx.x;
    for (int j = t; j < LPB*NF; j += 512) acc[j] = 0.f;
    for (int j = t; j < MAXPIX; j += 512) s_tk[j] = -1;
    for (int j = t; j < 8*LPB*9; j += 512) ((int*)h8)[j] = 0;
    for (int j = t; j < 8*LPB; j += 512) ((int*)qc)[j] = 0;
    __syncthreads();
    if (t < NF) {                            // static table (cnt == MAXPIX)
        const float Lf = (float)MAXPIX;
        float p = ((float)t + 0.5f) * (Lf / (float)NF) - 0.5f;
        p = fminf(fmaxf(p, 0.0f), Lf - 1.0f);
        int i0 = (int)floorf(p);
        int i1 = min(i0 + 1, MAXPIX - 1);
        float wg = p - (float)i0;
        s_tk[i0] = t; s_tw[i0] = 1.0f - wg;  // spacing 5.12 => no collision
        s_tk[i1] = t; s_tw[i1] = wg;
    }
    long base = (long)gb * BTOT;
    const int qsz = BTOT / 8;                // 2048 (exact => no bounds checks)
    int qbeg = w * qsz;
    const int nit = qsz / 64;                // 32
    unsigned long long ltmask = (1ull << lane) - 1ull;
    // phase 1: per-segment per-label counts via ballot leaders; cache meta 4/int
    unsigned m4[nit/4];
    #pragma unroll
    for (int j = 0; j < nit/4; ++j) m4[j] = 0u;
    #pragma unroll 4
    for (int it = 0; it < nit; ++it) {
        int meta = (int)rmeta[base + qbeg + it*64 + lane];
        m4[it >> 2] |= (unsigned)meta << (8*(it & 3));
        unsigned long long m = match_bits<4>(meta & 15);
        int cb = __popcll(m & ltmask);
        if (cb == 0) qc[w][meta & 15] += __popcll(m);   // distinct addrs per leader
    }
    __syncthreads();
    if (t < LPB) {
        int s = 0;
        #pragma unroll
        for (int q = 0; q < 8; ++q) { cur[q][t] = s; s += qc[q][t]; }
    }
    __syncthreads();
    // phase 2: stable rank + reduce; shared low-4 ballots for rank & hist
    #pragma unroll 4
    for (int it = 0; it < nit; ++it) {
        int meta = (int)(m4[it >> 2] >> (8*(it & 3))) & 255;
        float iv = riv[base + qbeg + it*64 + lane];
        int ll = meta & 15;
        unsigned long long mll = ~0ull, m8;
        #pragma unroll
        for (int bit = 0; bit < 4; ++bit) {
            unsigned long long bb = __ballot((meta >> bit) & 1);
            mll &= ((meta >> bit) & 1) ? bb : ~bb;
        }
        m8 = mll;
        #pragma unroll
        for (int bit = 4; bit < 8; ++bit) {
            unsigned long long bb = __ballot((meta >> bit) & 1);
            m8 &= ((meta >> bit) & 1) ? bb : ~bb;
        }
        int cb = __popcll(mll & ltmask);
        int ct = __popcll(mll);
        int r0 = cur[w][ll];
        int rank = r0 + cb;
        if (cb == ct - 1) cur[w][ll] = r0 + ct;
        if (__popcll(m8 & ltmask) == 0)                 // (ll,bin) leader
            h8[w][ll*9 + (meta >> 4)] += __popcll(m8);
        int k = s_tk[rank];
        if (k >= 0) atomicAdd(&acc[ll*NF + k], iv * s_tw[rank]);  // commutative-exact pair
    }
    __syncthreads();
    if (t < FEAT) {
        for (int r = 0; r < LPB; ++r) {
            float v;
            if (t < NF) v = acc[r*NF + t];
            else {
                int hsum = 0;
                #pragma unroll
                for (int q = 0; q < 8; ++q) hsum += h8[q][r*9 + (t - NF)];
                v = (float)hsum;
            }
            long gl = (long)gb * LPB + r;
            out[gl * FEAT + t] = v;
        }
    }
}

// ---- edges: top-2 nearest centers (bbox2 x/y LDS-staged) ------------------
__device__ __forceinline__ bool better(float d, int j, float d2, int j2) {
    return d < d2 || (d == d2 && j < j2);
}

__global__ void __launch_bounds__(256) edge_kernel(const float* __restrict__ bbox1,
                                                   const float* __restrict__ bbox2,
                                                   const float* __restrict__ zfm,
                                                   float* __restrict__ out) {
    __shared__ float sbx[NI], sby[NI];       // 32 KB
    int wave = threadIdx.x >> 6, lane = threadIdx.x & 63;
    for (int r = threadIdx.x; r < NI; r += 256) {
        float4 b = ((const float4*)bbox2)[r];
        sbx[r] = b.x; sby[r] = b.y;
    }
    __syncthreads();
    int i = blockIdx.x * 4 + wave;
    float c1x = bbox1[i*4 + 0], c1y = bbox1[i*4 + 1];
    float d0 = INFINITY; int j0 = 0x7fffffff;
    float d1 = INFINITY; int j1 = 0x7fffffff;
    for (int t = 0; t < NI; t += 64) {
        int j = t + lane;
        float dx = c1x - sbx[j];
        float dy = c1y - sby[j];
        float dsq = dx*dx + dy*dy;                 // no fma (contract off)
        float d = (float)sqrt((double)dsq);        // correctly-rounded f32 sqrt
        if (better(d, j, d0, j0)) { d1 = d0; j1 = j0; d0 = d; j0 = j; }
        else if (better(d, j, d1, j1)) { d1 = d; j1 = j; }
    }
    for (int off = 32; off; off >>= 1) {
        float od0 = __shfl_down(d0, off); int oj0 = __shfl_down(j0, off);
        float od1 = __shfl_down(d1, off); int oj1 = __shfl_down(j1, off);
        if (better(od0, oj0, d0, j0)) {
            if (better(d0, j0, od1, oj1)) { d1 = d0; j1 = j0; }
            else                          { d1 = od1; j1 = oj1; }
            d0 = od0; j0 = oj0;
        } else if (better(od0, oj0, d1, j1)) { d1 = od0; j1 = oj0; }
    }
    if (lane == 0) {
        float z1 = zfm[i];
        int js[2] = { j0, j1 };
        for (int t = 0; t < 2; ++t) {
            int e = i*2 + t, j = js[t];
            out[EIOFF + e]      = (float)i;
            out[EIOFF + NE + e] = (float)(j + NI);
            float* ea = out + EAOFF + (long)e * 6;
            ea[0] = z1;
            ea[1] = zfm[NI + j];
            ea[2] = c1x - bbox2[j*4 + 0];
            ea[3] = c1y - bbox2[j*4 + 1];
            ea[4] = bbox1[i*4 + 2] / bbox2[j*4 + 2];
            ea[5] = bbox1[i*4 + 3] / bbox2[j*4 + 3];
        }
    }
}

extern "C" void kernel_launch(void* const* d_in, const int* in_sizes, int n_in,
                              void* d_out, int out_size, void* d_ws, size_t ws_size,
                              hipStream_t stream) {
    const float* img1  = (const float*)d_in[0];
    const float* img2  = (const float*)d_in[1];
    const float* flow1 = (const float*)d_in[2];
    const float* flow2 = (const float*)d_in[3];
    const float* bbox1 = (const float*)d_in[4];
    const float* bbox2 = (const float*)d_in[5];
    const int*   mask1 = (const int*)d_in[6];
    const int*   mask2 = (const int*)d_in[7];
    float* out = (float*)d_out;

    char* ws = (char*)d_ws;
    size_t off = 0;
    unsigned* cntA   = (unsigned*)(ws + off); off += (size_t)TOTCHK * NBPI * 4;  // 1 MB
    float*    riv    = (float*)(ws + off);    off += (size_t)REC * 4;            // 33.5 MB
    float*    zfpart = (float*)(ws + off);    off += (size_t)CBLK * NI * 4;      // 4.2 MB
    float*    zfm    = (float*)(ws + off);    off += 2 * NI * 4;
    unsigned char* rmeta = (unsigned char*)(ws + off); off += (size_t)REC;       // 8.4 MB

    hipLaunchKernelGGL(count_zf_kernel, dim3(CBLK), dim3(256), 0, stream,
                       mask1, mask2, flow1, flow2, cntA, zfpart);
    hipLaunchKernelGGL(scan1_zf_kernel, dim3(NBG), dim3(256), 0, stream,
                       cntA, zfpart, zfm);
    hipLaunchKernelGGL(sort_kernel, dim3(TOTCHK), dim3(512), 0, stream,
                       img1, img2, flow1, flow2, mask1, mask2, cntA, riv, rmeta);
    hipLaunchKernelGGL(stageB_kernel, dim3(NBG), dim3(512), 0, stream,
                       riv, rmeta, out);
    hipLaunchKernelGGL(edge_kernel, dim3(NI/4), dim3(256), 0, stream,
                       bbox1, bbox2, zfm, out);
}

// Round 3
// 301.196 us; speedup vs baseline: 1.1574x; 1.0336x over previous
//
#include <hip/hip_runtime.h>
#include <math.h>

#pragma clang fp contract(off)

#define HW      (2048*2048)
#define NI      4096        // instances per image
#define MAXPIX  1024        // pixels per instance (equal partition)
#define NF      200
#define FEAT    209
#define NE      (NI*2)
#define XSIZE   ((2*NI)*FEAT)
#define EIOFF   XSIZE
#define EAOFF   (EIOFF + 2*NE)

#define S       8192        // pixels per chunk (one sort block)
#define CHK     (HW/S)      // 512 chunks per image
#define TOTCHK  (2*CHK)     // 1024
#define NBPI    256         // buckets per image (16 labels each)
#define LPB     16
#define NBG     (2*NBPI)    // 512 global buckets
#define REC     (2*HW)
#define BTOT    (LPB*MAXPIX) // 16384 records per bucket (equal partition => static)

template<int NB>
__device__ __forceinline__ unsigned long long match_bits(int v) {
    unsigned long long m = ~0ull;
    #pragma unroll
    for (int bit = 0; bit < NB; ++bit) {
        unsigned long long bb = __ballot((v >> bit) & 1);
        m &= ((v >> bit) & 1) ? bb : ~bb;
    }
    return m;
}

// ---- pass 1: per-chunk bucket counts + per-block per-label fz partials ---
// one block per sort chunk (1024 blocks, 4/CU): 4 waves split the 8192 px.
__global__ void __launch_bounds__(256) count_zf_kernel(const int* __restrict__ mask1,
        const int* __restrict__ mask2, const float* __restrict__ flow1,
        const float* __restrict__ flow2, unsigned* __restrict__ cntA,
        float* __restrict__ zfpart) {
    __shared__ unsigned cnt[4][NBPI];    // 4 KB
    __shared__ float zfp[NI];            // 16 KB
    int w = threadIdx.x >> 6, lane = threadIdx.x & 63;
    for (int j = threadIdx.x; j < 4*NBPI; j += 256) ((unsigned*)cnt)[j] = 0u;
    for (int j = threadIdx.x; j < NI; j += 256) zfp[j] = 0.f;
    __syncthreads();
    int c = blockIdx.x;
    int img = c / CHK;
    const int4*   mask  = (const int4*)(img ? mask2 : mask1);
    const float4* flowz = (const float4*)((img ? flow2 : flow1) + 2L*HW);
    long base4 = (long)(c - img*CHK) * (S/4) + (long)w * (S/16);  // per-wave quarter
    for (int t = 0; t < S/16; t += 64) {
        int4   l4 = mask[base4 + t + lane];
        float4 fz = flowz[base4 + t + lane];
        atomicAdd(&cnt[w][(l4.x-1) >> 4], 1u);
        atomicAdd(&cnt[w][(l4.y-1) >> 4], 1u);
        atomicAdd(&cnt[w][(l4.z-1) >> 4], 1u);
        atomicAdd(&cnt[w][(l4.w-1) >> 4], 1u);
        atomicAdd(&zfp[l4.x-1], fz.x);
        atomicAdd(&zfp[l4.y-1], fz.y);
        atomicAdd(&zfp[l4.z-1], fz.z);
        atomicAdd(&zfp[l4.w-1], fz.w);
    }
    __syncthreads();
    unsigned* dst = cntA + (long)c * NBPI;
    for (int j = threadIdx.x; j < NBPI; j += 256)
        dst[j] = cnt[0][j] + cnt[1][j] + cnt[2][j] + cnt[3][j];
    float* zdst = zfpart + (long)c * NI;
    for (int j = threadIdx.x; j < NI; j += 256) zdst[j] = zfp[j];
}

// ---- pass 2: per-bucket chunk scan (shfl) + fused zf means ---------------
__global__ void __launch_bounds__(256) scan1_zf_kernel(unsigned* __restrict__ cntA,
        const float* __restrict__ zfpart, float* __restrict__ zfm) {
    __shared__ int wsum[4];
    __shared__ float zpar[16][LPB];
    int gb = blockIdx.x;
    int img = gb >> 8, lb = gb & (NBPI - 1);
    int t = threadIdx.x, lane = t & 63, w = t >> 6;
    const int PER = CHK / 256;   // 2 chunks per thread
    unsigned e[PER]; int s = 0;
    long base = ((long)img * CHK + (long)t * PER) * NBPI + lb;
    #pragma unroll
    for (int i = 0; i < PER; ++i) { e[i] = cntA[base + (long)i * NBPI]; s += (int)e[i]; }
    int incl = s;
    #pragma unroll
    for (int off = 1; off < 64; off <<= 1) {
        int o = __shfl_up(incl, off);
        if (lane >= off) incl += o;
    }
    if (lane == 63) wsum[w] = incl;
    __syncthreads();
    int add = 0;
    for (int q = 0; q < w; ++q) add += wsum[q];
    unsigned pre = (unsigned)(incl + add - s);
    #pragma unroll
    for (int i = 0; i < PER; ++i) { unsigned cv = e[i]; cntA[base + (long)i * NBPI] = pre; pre += cv; }
    // fused zf reduction: this bucket's 16 labels over 512 partial rows
    {
        int l0 = (gb * LPB) & (NI-1);
        int lab = t & 15, rg = t >> 4;           // 16 row-groups x 16 labels
        const float* zp = zfpart + ((long)img*CHK + rg*32)*NI + l0 + lab;
        float s32 = 0.f;
        #pragma unroll
        for (int k = 0; k < 32; ++k) s32 += zp[(long)k*NI];
        zpar[rg][lab] = s32;
    }
    __syncthreads();
    if (t < LPB) {
        float sum = 0.f;
        #pragma unroll
        for (int g = 0; g < 16; ++g) sum += zpar[g][t];
        zfm[gb*LPB + t] = sum * (1.0f/(float)MAXPIX);   // exact /1024
    }
}

// ---- pass 3: LDS-staged stable bucket sort (53248 B LDS => 3 blocks/CU) --
__global__ void __launch_bounds__(512) sort_kernel(
        const float* __restrict__ img1, const float* __restrict__ img2,
        const float* __restrict__ flow1, const float* __restrict__ flow2,
        const int* __restrict__ mask1, const int* __restrict__ mask2,
        const unsigned* __restrict__ cntA,
        float* __restrict__ riv, unsigned char* __restrict__ rmeta) {
    __shared__ float ivs[S];                     // 32 KB
    __shared__ unsigned short smeta[S];          // 16 KB  (bkt<<8 | bin<<4 | ll)
    __shared__ unsigned short cw[8][NBPI];       // 4 KB   => 53248 B total
    int* wsum  = (int*)smeta;                    // alias: smeta dead until phase 2
    int* gofsA = (int*)cw;                       // alias: cw dead after phase 2
    int t = threadIdx.x, w = t >> 6, lane = t & 63;
    int c = blockIdx.x;
    int img = c / CHK;
    const int*   mask  = img ? mask2  : mask1;
    const float* image = img ? img2   : img1;
    const float* flow  = img ? flow2  : flow1;
    long base = (long)(c - img*CHK) * S;
    unsigned pre = 0;
    if (t < NBPI) pre = cntA[(long)c * NBPI + t];      // early global load
    for (int j = t; j < 8*NBPI; j += 512) ((unsigned short*)cw)[j] = 0;
    __syncthreads();
    // phase 1: prefetch everything + ballots; pack l|bin|cb|ct into one reg
    long qbase = base + (long)w * (S/8);
    int   pk[16];
    float piv[16];
    unsigned long long ltmask = (1ull << lane) - 1ull;
    #pragma unroll
    for (int it = 0; it < 16; ++it) {
        long p = qbase + it*64 + lane;
        int l = mask[p] - 1;
        piv[it] = image[p];
        float fx = flow[p], fy = flow[HW + p];
        int cx = fx < 0.f ? 0 : (fx == 0.f ? 1 : 2);
        int cy = fy < 0.f ? 0 : (fy == 0.f ? 1 : 2);
        int bkt = l >> 4;
        unsigned long long m = match_bits<8>(bkt);
        int cb = __popcll(m & ltmask);
        int ct = __popcll(m);
        pk[it] = l | ((cx*3 + cy) << 12) | (cb << 16) | (ct << 22);
        if (cb == 0) cw[w][bkt] += (unsigned short)ct;   // leaders: distinct addrs
    }
    __syncthreads();
    // block scan over 256 buckets via wave shfl (threads 0..255 = 4 waves)
    int tot = 0, incl = 0;
    if (t < NBPI) {
        #pragma unroll
        for (int q = 0; q < 8; ++q) tot += cw[q][t];
        incl = tot;
        #pragma unroll
        for (int off = 1; off < 64; off <<= 1) {
            int o = __shfl_up(incl, off);
            if (lane >= off) incl += o;
        }
        if (lane == 63) wsum[w] = incl;
    }
    __syncthreads();
    int gof = 0;
    if (t < NBPI) {
        int add = 0;
        for (int q = 0; q < w; ++q) add += wsum[q];
        int excl = incl + add - tot;                 // chunk-local bucket offset
        int run = excl;
        #pragma unroll
        for (int q = 0; q < 8; ++q) {
            int cq = cw[q][t];
            cw[q][t] = (unsigned short)run;
            run += cq;
        }
        gof = (img*NBPI + t) * BTOT + (int)pre - excl;   // static bucketBase
    }
    __syncthreads();
    // phase 2: place records (no loads, no ballots — all cached in pk/piv)
    #pragma unroll
    for (int it = 0; it < 16; ++it) {
        int pkv = pk[it];
        int l = pkv & 4095, bin = (pkv >> 12) & 15;
        int cb = (pkv >> 16) & 63, ct = (pkv >> 22) & 127;
        int bkt = l >> 4;
        int r0 = (int)cw[w][bkt];
        int dst = r0 + cb;
        if (cb == ct - 1) cw[w][bkt] = (unsigned short)(r0 + ct);
        ivs[dst] = piv[it];
        smeta[dst] = (unsigned short)((bkt << 8) | (bin << 4) | (l & 15));
    }
    __syncthreads();
    if (t < NBPI) gofsA[t] = gof;                    // cw region now dead
    __syncthreads();
    // phase 3: linear flush — consecutive j => contiguous global runs (32 recs)
    for (int j = t; j < S; j += 512) {
        int ms = (int)smeta[j];
        int b = ms >> 8;
        int g = gofsA[b] + j;
        riv[g]   = ivs[j];
        rmeta[g] = (unsigned char)(ms & 0xFF);
    }
}

// ---- pass 4: fused rank + features; 1024 threads, 2 blocks/CU ------------
__global__ void __launch_bounds__(1024) stageB_kernel(
        const float* __restrict__ riv, const unsigned char* __restrict__ rmeta,
        float* __restrict__ out) {
    __shared__ float acc[LPB * NF];          // 12.8 KB
    __shared__ float s_tw[MAXPIX];           // 4 KB
    __shared__ int   s_tk[MAXPIX];           // 4 KB
    __shared__ int   hist[LPB * 9];          // 576 B
    __shared__ int   qc[16][LPB];            // 1 KB
    __shared__ int   cur[16][LPB];           // 1 KB
    int t = threadIdx.x, w = t >> 6, lane = t & 63;
    int gb = blockIdx.x;
    for (int j = t; j < LPB*NF; j += 1024) acc[j] = 0.f;
    if (t < MAXPIX) s_tk[t] = -1;
    if (t < LPB*9) hist[t] = 0;
    for (int j = t; j < 16*LPB; j += 1024) ((int*)qc)[j] = 0;
    __syncthreads();
    if (t < NF) {                            // static table (cnt == MAXPIX)
        const float Lf = (float)MAXPIX;
        float p = ((float)t + 0.5f) * (Lf / (float)NF) - 0.5f;
        p = fminf(fmaxf(p, 0.0f), Lf - 1.0f);
        int i0 = (int)floorf(p);
        int i1 = min(i0 + 1, MAXPIX - 1);
        float wg = p - (float)i0;
        s_tk[i0] = t; s_tw[i0] = 1.0f - wg;  // spacing 5.12 => no collision
        s_tk[i1] = t; s_tw[i1] = wg;
    }
    long base = (long)gb * BTOT;
    const int qsz = BTOT / 16;               // 1024 per wave segment (exact)
    int qbeg = w * qsz;
    const int nit = qsz / 64;                // 16
    unsigned long long ltmask = (1ull << lane) - 1ull;
    // phase 1: per-segment per-label counts — uchar4 loads + LDS atomics
    {
        const uchar4* rm4 = (const uchar4*)(rmeta + base + qbeg);
        #pragma unroll
        for (int it = 0; it < nit/4; ++it) {
            uchar4 m = rm4[it*64 + lane];
            atomicAdd(&qc[w][m.x & 15], 1);
            atomicAdd(&qc[w][m.y & 15], 1);
            atomicAdd(&qc[w][m.z & 15], 1);
            atomicAdd(&qc[w][m.w & 15], 1);
        }
    }
    __syncthreads();
    if (t < LPB) {
        int s = 0;
        #pragma unroll
        for (int q = 0; q < 16; ++q) { cur[q][t] = s; s += qc[q][t]; }
    }
    __syncthreads();
    // phase 2: stable rank + reduce (rmeta re-read is L1-hot: 16 KB/block)
    #pragma unroll 4
    for (int it = 0; it < nit; ++it) {
        int i = qbeg + it*64 + lane;
        int meta = (int)rmeta[base + i];
        float iv = riv[base + i];
        int ll = meta & 15;
        unsigned long long m = match_bits<4>(ll);
        int cb = __popcll(m & ltmask);
        int ct = __popcll(m);
        int r0 = cur[w][ll];
        int rank = r0 + cb;
        if (cb == ct - 1) cur[w][ll] = r0 + ct;
        atomicAdd(&hist[ll*9 + (meta >> 4)], 1);
        int k = s_tk[rank];
        if (k >= 0) atomicAdd(&acc[ll*NF + k], iv * s_tw[rank]);  // commutative-exact pair
    }
    __syncthreads();
    // epilogue: fully contiguous 16x209 block write
    for (int j = t; j < LPB*FEAT; j += 1024) {
        int r = j / FEAT, k = j - r*FEAT;
        float v = (k < NF) ? acc[r*NF + k] : (float)hist[r*9 + (k - NF)];
        out[(long)gb * LPB * FEAT + j] = v;
    }
}

// ---- edges: top-2 nearest centers (bbox2 x/y LDS-staged) ------------------
__device__ __forceinline__ bool better(float d, int j, float d2, int j2) {
    return d < d2 || (d == d2 && j < j2);
}

__global__ void __launch_bounds__(256) edge_kernel(const float* __restrict__ bbox1,
                                                   const float* __restrict__ bbox2,
                                                   const float* __restrict__ zfm,
                                                   float* __restrict__ out) {
    __shared__ float sbx[NI], sby[NI];       // 32 KB
    int wave = threadIdx.x >> 6, lane = threadIdx.x & 63;
    for (int r = threadIdx.x; r < NI; r += 256) {
        float4 b = ((const float4*)bbox2)[r];
        sbx[r] = b.x; sby[r] = b.y;
    }
    __syncthreads();
    int i = blockIdx.x * 4 + wave;
    float c1x = bbox1[i*4 + 0], c1y = bbox1[i*4 + 1];
    float d0 = INFINITY; int j0 = 0x7fffffff;
    float d1 = INFINITY; int j1 = 0x7fffffff;
    for (int t = 0; t < NI; t += 64) {
        int j = t + lane;
        float dx = c1x - sbx[j];
        float dy = c1y - sby[j];
        float dsq = dx*dx + dy*dy;                 // no fma (contract off)
        float d = (float)sqrt((double)dsq);        // correctly-rounded f32 sqrt
        if (better(d, j, d0, j0)) { d1 = d0; j1 = j0; d0 = d; j0 = j; }
        else if (better(d, j, d1, j1)) { d1 = d; j1 = j; }
    }
    for (int off = 32; off; off >>= 1) {
        float od0 = __shfl_down(d0, off); int oj0 = __shfl_down(j0, off);
        float od1 = __shfl_down(d1, off); int oj1 = __shfl_down(j1, off);
        if (better(od0, oj0, d0, j0)) {
            if (better(d0, j0, od1, oj1)) { d1 = d0; j1 = j0; }
            else                          { d1 = od1; j1 = oj1; }
            d0 = od0; j0 = oj0;
        } else if (better(od0, oj0, d1, j1)) { d1 = od0; j1 = oj0; }
    }
    if (lane == 0) {
        float z1 = zfm[i];
        int js[2] = { j0, j1 };
        for (int t = 0; t < 2; ++t) {
            int e = i*2 + t, j = js[t];
            out[EIOFF + e]      = (float)i;
            out[EIOFF + NE + e] = (float)(j + NI);
            float* ea = out + EAOFF + (long)e * 6;
            ea[0] = z1;
            ea[1] = zfm[NI + j];
            ea[2] = c1x - bbox2[j*4 + 0];
            ea[3] = c1y - bbox2[j*4 + 1];
            ea[4] = bbox1[i*4 + 2] / bbox2[j*4 + 2];
            ea[5] = bbox1[i*4 + 3] / bbox2[j*4 + 3];
        }
    }
}

extern "C" void kernel_launch(void* const* d_in, const int* in_sizes, int n_in,
                              void* d_out, int out_size, void* d_ws, size_t ws_size,
                              hipStream_t stream) {
    const float* img1  = (const float*)d_in[0];
    const float* img2  = (const float*)d_in[1];
    const float* flow1 = (const float*)d_in[2];
    const float* flow2 = (const float*)d_in[3];
    const float* bbox1 = (const float*)d_in[4];
    const float* bbox2 = (const float*)d_in[5];
    const int*   mask1 = (const int*)d_in[6];
    const int*   mask2 = (const int*)d_in[7];
    float* out = (float*)d_out;

    char* ws = (char*)d_ws;
    size_t off = 0;
    unsigned* cntA   = (unsigned*)(ws + off); off += (size_t)TOTCHK * NBPI * 4;  // 1 MB
    float*    riv    = (float*)(ws + off);    off += (size_t)REC * 4;            // 33.5 MB
    float*    zfpart = (float*)(ws + off);    off += (size_t)TOTCHK * NI * 4;    // 16.8 MB
    float*    zfm    = (float*)(ws + off);    off += 2 * NI * 4;
    unsigned char* rmeta = (unsigned char*)(ws + off); off += (size_t)REC;       // 8.4 MB

    hipLaunchKernelGGL(count_zf_kernel, dim3(TOTCHK), dim3(256), 0, stream,
                       mask1, mask2, flow1, flow2, cntA, zfpart);
    hipLaunchKernelGGL(scan1_zf_kernel, dim3(NBG), dim3(256), 0, stream,
                       cntA, zfpart, zfm);
    hipLaunchKernelGGL(sort_kernel, dim3(TOTCHK), dim3(512), 0, stream,
                       img1, img2, flow1, flow2, mask1, mask2, cntA, riv, rmeta);
    hipLaunchKernelGGL(stageB_kernel, dim3(NBG), dim3(1024), 0, stream,
                       riv, rmeta, out);
    hipLaunchKernelGGL(edge_kernel, dim3(NI/4), dim3(256), 0, stream,
                       bbox1, bbox2, zfm, out);
}